// Round 5
// baseline (9554.152 us; speedup 1.0000x reference)
//
#include <hip/hip_runtime.h>
#include <stdint.h>

#define N_TOK   16384
#define DIM     512
#define K_CODES 8192
#define TT      16     // tokens per block
#define CT      16     // codes per tile
#define KH      256    // k-dimension half
#define XPAD    516    // Xs row stride (floats): 4*row%32 spread, 16B-aligned
#define EPAD    260    // Es row stride (floats): 4*row%32 spread, 16B-aligned

// ---------------- kernel 1: exact fp64 distance + argmin ----------------
// Inputs are fp32 (per the reference: jax.random.normal(..., dtype=float32)).
// Distances accumulated in fp64 => exact ordering; ties -> lowest index.
// LDS: Xs 16x516 fl (33.0 KB, resident) + Es 16x260 fl (16.6 KB, per k-half)
//      + cand arrays 3 KB  => 52.7 KB < 64 KB static limit.
__global__ __launch_bounds__(256) void brute_argmin_kernel(
    const float* __restrict__ xs,
    const float* __restrict__ ew,
    unsigned int* __restrict__ g_idx) {
  __shared__ __align__(16) float Xs[TT * XPAD];
  __shared__ __align__(16) float Es[CT * EPAD];
  __shared__ double cand_v[256];
  __shared__ unsigned int cand_i[256];

  const int t = threadIdx.x;
  const int tok0 = blockIdx.x * TT;

  // stage the block's 16 token rows (16 x 512 floats), coalesced
#pragma unroll
  for (int i = 0; i < 32; ++i) {
    const int idx = i * 256 + t;            // 0..8191
    const int row = idx >> 9, col = idx & 511;
    Xs[row * XPAD + col] = xs[(size_t)(tok0 + row) * DIM + col];
  }

  const int tt = t >> 4;    // my token (0..15)
  const int cl = t & 15;    // my code lane within tile (0..15)
  double bv = __builtin_inf();
  unsigned int bi = 0u;

  for (int c0 = 0; c0 < K_CODES; c0 += CT) {
    double s0 = 0.0, s1 = 0.0, s2 = 0.0, s3 = 0.0;
#pragma unroll
    for (int h = 0; h < 2; ++h) {
      __syncthreads();   // previous phase's reads (and X staging) complete
      // stage 16 code rows x 256 floats (one k-half)
#pragma unroll
      for (int i = 0; i < 16; ++i) {
        const int idx = i * 256 + t;        // 0..4095
        const int row = idx >> 8, col = idx & 255;
        Es[row * EPAD + col] = ew[(size_t)(c0 + row) * DIM + h * KH + col];
      }
      __syncthreads();

      const float* __restrict__ xr = &Xs[tt * XPAD + h * KH];
      const float* __restrict__ er = &Es[cl * EPAD];
#pragma unroll 8
      for (int d = 0; d < KH; d += 4) {
        const float4 xf = *(const float4*)(xr + d);
        const float4 ef = *(const float4*)(er + d);
        const double a0 = (double)xf.x - (double)ef.x;
        const double a1 = (double)xf.y - (double)ef.y;
        const double a2 = (double)xf.z - (double)ef.z;
        const double a3 = (double)xf.w - (double)ef.w;
        s0 = fma(a0, a0, s0);
        s1 = fma(a1, a1, s1);
        s2 = fma(a2, a2, s2);
        s3 = fma(a3, a3, s3);
      }
    }
    const double s = (s0 + s1) + (s2 + s3);
    // ascending c0 + strict < => first-occurrence tie rule within this thread
    if (s < bv) { bv = s; bi = (unsigned int)(c0 + cl); }
  }

  cand_v[t] = bv;
  cand_i[t] = bi;
  __syncthreads();
  if (t < TT) {
    double mv = __builtin_inf();
    unsigned int mi = 0xFFFFFFFFu;
#pragma unroll
    for (int j = 0; j < 16; ++j) {
      const double v = cand_v[t * 16 + j];
      const unsigned int i = cand_i[t * 16 + j];
      if (v < mv || (v == mv && i < mi)) { mv = v; mi = i; }
    }
    g_idx[tok0 + t] = mi;
  }
}

// ---------------- kernel 2: gather (bitwise fp32) + loss partials ----------------
__global__ __launch_bounds__(256) void gather_loss_kernel(
    const float* __restrict__ xs,
    const float* __restrict__ ew,
    const unsigned int* __restrict__ g_idx,
    float* __restrict__ out,
    float* __restrict__ loss_acc) {
  const int row = blockIdx.x;
  const int t = threadIdx.x;  // 256 threads, 2 floats each
  const unsigned int idx = g_idx[row];
  const float2 ev = ((const float2*)(ew + (size_t)idx * DIM))[t];
  const float2 xv = ((const float2*)(xs + (size_t)row * DIM))[t];
  ((float2*)(out + (size_t)row * DIM))[t] = ev;   // bitwise-exact gather
  const float d0 = ev.x - xv.x;
  const float d1 = ev.y - xv.y;
  float s = fmaf(d0, d0, d1 * d1);
#pragma unroll
  for (int off = 32; off > 0; off >>= 1) s += __shfl_down(s, off, 64);
  __shared__ float wsum[4];
  if ((t & 63) == 0) wsum[t >> 6] = s;
  __syncthreads();
  if (t == 0) atomicAdd(loss_acc, wsum[0] + wsum[1] + wsum[2] + wsum[3]);
}

// ---------------- kernel 3: finalize loss ----------------
__global__ void loss_finalize(const float* __restrict__ loss_acc,
                              float* __restrict__ out, int out_size) {
  if (threadIdx.x == 0 && blockIdx.x == 0) {
    out[out_size - 1] = *loss_acc * 1.25f / (float)((size_t)N_TOK * DIM);
  }
}

extern "C" void kernel_launch(void* const* d_in, const int* in_sizes, int n_in,
                              void* d_out, int out_size, void* d_ws, size_t ws_size,
                              hipStream_t stream) {
  const float* xs = (const float*)d_in[0];
  const float* ew = (const float*)d_in[1];
  // defensive: identify inputs by element count (xs: N*D, ew: K*D)
  if (n_in >= 2 && in_sizes[0] == K_CODES * DIM && in_sizes[1] == N_TOK * DIM) {
    const float* tmp = xs; xs = ew; ew = tmp;
  }
  float* out = (float*)d_out;

  // ws: [0, N*4) argmin idx | [N*4, +4) loss accumulator
  unsigned int* g_idx = (unsigned int*)d_ws;
  float* loss_acc = (float*)((char*)d_ws + (size_t)N_TOK * 4);

  hipMemsetAsync(loss_acc, 0, 4, stream);

  brute_argmin_kernel<<<N_TOK / TT, 256, 0, stream>>>(xs, ew, g_idx);
  gather_loss_kernel<<<N_TOK, 256, 0, stream>>>(xs, ew, g_idx, out, loss_acc);
  loss_finalize<<<1, 64, 0, stream>>>(loss_acc, out, out_size);
}

// Round 7
// 926.858 us; speedup vs baseline: 10.3081x; 10.3081x over previous
//
#include <hip/hip_runtime.h>
#include <stdint.h>

#define N_TOK   16384
#define DIM     512
#define KAUG    1024     // packed layout: [hi | lo] bf16
#define KEFF    1536     // 3 phases: xh*eh + xh*el + xl*eh
#define K_CODES 8192
#define BM      128
#define BN      128
#define BK      32
#define NT      2        // BN-tiles per block (chunk = 256 codes)
#define NCHUNK  32
#define MU      0.02f    // rerank margin (score err ~3e-4 sigma, ~1.5e-3 @5sig)

typedef __attribute__((ext_vector_type(8))) short bf16x8;
typedef __attribute__((ext_vector_type(4))) float f32x4;

__device__ __forceinline__ float bf2f(unsigned short u) {
  return __uint_as_float(((unsigned int)u) << 16);
}
__device__ __forceinline__ unsigned short f2bf_rne(float f) {
  unsigned int u = __float_as_uint(f);
  unsigned int r = (u + 0x7FFFu + ((u >> 16) & 1u)) >> 16;
  return (unsigned short)r;
}
__device__ __forceinline__ unsigned int fmono(float f) {
  unsigned int b = __float_as_uint(f);
  unsigned int mask = ((int)b < 0) ? 0xFFFFFFFFu : 0x80000000u;
  return b ^ mask;
}
__device__ __forceinline__ float finv(unsigned int m) {
  return (m & 0x80000000u) ? __uint_as_float(m ^ 0x80000000u)
                           : __uint_as_float(~m);
}
__device__ __forceinline__ void async16(const void* gptr, void* lptr) {
  __builtin_amdgcn_global_load_lds(
      (const __attribute__((address_space(1))) unsigned int*)gptr,
      (__attribute__((address_space(3))) unsigned int*)lptr,
      16, 0, 0);
}

// ---------------- split: fp32 row[512] -> bf16 row[1024] = [hi|lo] ----------------
__global__ __launch_bounds__(256) void split_kernel(
    const float* __restrict__ in, unsigned short* __restrict__ out, int nrows) {
  const int gid = blockIdx.x * 256 + threadIdx.x;   // one float4 each
  if (gid >= nrows * 128) return;
  const int row = gid >> 7;
  const int c4 = (gid & 127) * 4;
  const float4 v = ((const float4*)in)[gid];
  const float vv[4] = {v.x, v.y, v.z, v.w};
  ushort4 h, l;
  unsigned short hh[4], ll[4];
#pragma unroll
  for (int k = 0; k < 4; ++k) {
    hh[k] = f2bf_rne(vv[k]);
    const float hf = bf2f(hh[k]);
    ll[k] = f2bf_rne(vv[k] - hf);   // v-hf exact (Sterbenz)
  }
  h.x = hh[0]; h.y = hh[1]; h.z = hh[2]; h.w = hh[3];
  l.x = ll[0]; l.y = ll[1]; l.z = ll[2]; l.w = ll[3];
  *(ushort4*)(out + (size_t)row * KAUG + c4) = h;
  *(ushort4*)(out + (size_t)row * KAUG + 512 + c4) = l;
}

// ---------------- enorm: fp64-exact ||e_k||^2 -> fp32 ----------------
__global__ __launch_bounds__(256) void enorm_kernel(
    const float* __restrict__ ew, float* __restrict__ enorm) {
  const int lane = threadIdx.x & 63;
  const int wid  = threadIdx.x >> 6;
  const int row  = blockIdx.x * 4 + wid;
  const float4 v0 = *(const float4*)(ew + (size_t)row * DIM + lane * 8);
  const float4 v1 = *(const float4*)(ew + (size_t)row * DIM + lane * 8 + 4);
  const float f[8] = {v0.x, v0.y, v0.z, v0.w, v1.x, v1.y, v1.z, v1.w};
  double s = 0.0;
#pragma unroll
  for (int k = 0; k < 8; ++k) s = fma((double)f[k], (double)f[k], s);
#pragma unroll
  for (int off = 32; off > 0; off >>= 1) s += __shfl_down(s, off, 64);
  if (lane == 0) enorm[row] = (float)s;
}

// ---------------- main: K=1536 3-phase split GEMM + per-chunk top-2 ----------------
// score(i,k) = ||e_k||^2 - 2*(xh.eh + xh.el + xl.eh)   (err sigma ~3e-4)
__global__ __launch_bounds__(256) void gemm_top2_kernel(
    const unsigned short* __restrict__ X2,   // N x 1024 [hi|lo]
    const unsigned short* __restrict__ E2,   // K x 1024 [hi|lo]
    const float* __restrict__ enorm,
    unsigned long long* __restrict__ buf1,   // [token][32] packed top-1
    unsigned long long* __restrict__ buf2) { // [token][32] packed top-2
  __shared__ unsigned short As[BM * BK];
  __shared__ unsigned short Bs[BN * BK];
  __shared__ unsigned long long pack1[BM], pack2[BM], t1[BM], t2[BM];

  const int tid  = threadIdx.x;
  const int lane = tid & 63;
  const int wid  = tid >> 6;
  const int quad = lane >> 4;
  const int l15  = lane & 15;

  const int row0 = blockIdx.y * BM;

  if (tid < BM) { pack1[tid] = ~0ull; pack2[tid] = ~0ull; }

  const int wm = (wid >> 1) * 64;
  const int wn = (wid & 1) * 64;

  // staging (R1==R2==R3-verified): issue covers 16 rows x 64B; lane ->
  // row lane>>2, phys slot lane&3, fetched logical chunk (lane&3)^((lane>>3)&3)
  const int issue0 = wid * 2;
  const int srow   = lane >> 2;
  const int schunk = (lane & 3) ^ ((lane >> 3) & 3);

  for (int nt = 0; nt < NT; ++nt) {
    const int nbase = blockIdx.x * (BN * NT) + nt * BN;

    f32x4 acc[4][4];
#pragma unroll
    for (int i = 0; i < 4; ++i)
#pragma unroll
      for (int j = 0; j < 4; ++j) acc[i][j] = (f32x4){0.f, 0.f, 0.f, 0.f};

    if (tid < BM) { t1[tid] = ~0ull; t2[tid] = ~0ull; }

    for (int k0 = 0; k0 < KEFF; k0 += BK) {
      const int phase = k0 >> 9;            // 0: h.h, 1: h.l, 2: l.h
      const int kk = k0 & 511;
      const int acol = kk + ((phase == 2) ? 512 : 0);
      const int bcol = kk + ((phase == 1) ? 512 : 0);
#pragma unroll
      for (int q = 0; q < 2; ++q) {
        const int issue = issue0 + q;
        const int r = issue * 16 + srow;
        async16(X2 + (size_t)(row0 + r) * KAUG + acol + schunk * 8,
                (char*)As + issue * 1024);
        async16(E2 + (size_t)(nbase + r) * KAUG + bcol + schunk * 8,
                (char*)Bs + issue * 1024);
      }
      __syncthreads();
      bf16x8 a[4], b[4];
#pragma unroll
      for (int i = 0; i < 4; ++i) {
        const int ra = wm + i * 16 + l15;
        a[i] = *(const bf16x8*)((const char*)As + ra * 64 + ((quad ^ ((ra >> 1) & 3)) * 16));
        const int rb = wn + i * 16 + l15;
        b[i] = *(const bf16x8*)((const char*)Bs + rb * 64 + ((quad ^ ((rb >> 1) & 3)) * 16));
      }
#pragma unroll
      for (int i = 0; i < 4; ++i)
#pragma unroll
        for (int j = 0; j < 4; ++j)
          acc[i][j] = __builtin_amdgcn_mfma_f32_16x16x32_bf16(a[i], b[j], acc[i][j], 0, 0, 0);
      __syncthreads();
    }

    // epilogue: per-thread top-2 over j; two-phase LDS merge into t1/t2
    float en4[4];
#pragma unroll
    for (int j = 0; j < 4; ++j) en4[j] = enorm[nbase + wn + j * 16 + l15];

    unsigned long long mp1[4], mp2[4];
#pragma unroll
    for (int r = 0; r < 4; ++r) mp1[r] = mp2[r] = ~0ull;

#pragma unroll
    for (int i = 0; i < 4; ++i) {
      const int mrow = wm + i * 16 + quad * 4;
#pragma unroll
      for (int r = 0; r < 4; ++r) {
        float b1 = __builtin_inff(), b2v = __builtin_inff();
        unsigned int b1i = 0u, b2i = 0u;
#pragma unroll
        for (int j = 0; j < 4; ++j) {
          const float v = fmaf(-2.f, acc[i][j][r], en4[j]);
          const unsigned int ng = (unsigned int)(nbase + wn + j * 16 + l15);
          if (v < b1) { b2v = b1; b2i = b1i; b1 = v; b1i = ng; }
          else if (v < b2v) { b2v = v; b2i = ng; }
        }
        mp1[r] = ((unsigned long long)fmono(b1) << 32) | (unsigned long long)b1i;
        mp2[r] = ((unsigned long long)fmono(b2v) << 32) | (unsigned long long)b2i;
        atomicMin(&t1[mrow + r], mp1[r]);
      }
      __syncthreads();   // phase A done for this i's rows
#pragma unroll
      for (int r = 0; r < 4; ++r) {
        const unsigned int I1 = (unsigned int)t1[mrow + r];
        const unsigned long long cand =
            (((unsigned int)mp1[r]) == I1) ? mp2[r] : mp1[r];
        atomicMin(&t2[mrow + r], cand);
      }
      __syncthreads();
    }

    // streaming merge of (t1,t2) into running (pack1,pack2)
    if (tid < BM) {
      const unsigned long long a = t1[tid], b = t2[tid];
      const unsigned long long g1 = pack1[tid], g2 = pack2[tid];
      if (a < g1) { pack1[tid] = a; pack2[tid] = (g1 < b) ? g1 : b; }
      else        { pack2[tid] = (g2 < a) ? g2 : a; }
    }
    __syncthreads();   // merge reads t1/t2 done before next nt re-inits them
  }

  if (tid < BM) {
    buf1[(size_t)(row0 + tid) * NCHUNK + blockIdx.x] = pack1[tid];
    buf2[(size_t)(row0 + tid) * NCHUNK + blockIdx.x] = pack2[tid];
  }
}

// ---------------- rerank: 64 candidates/token, exact fp64 within margin ----------------
__global__ __launch_bounds__(256) void rerank_kernel(
    const float* __restrict__ xs, const float* __restrict__ ew,
    const unsigned long long* __restrict__ buf1,
    const unsigned long long* __restrict__ buf2,
    unsigned int* __restrict__ g_idx) {
  const int lane = threadIdx.x & 63;
  const int wv = threadIdx.x >> 6;
  const int tok = blockIdx.x * 4 + wv;
  const unsigned long long p = (lane < 32)
      ? buf1[(size_t)tok * NCHUNK + lane]
      : buf2[(size_t)tok * NCHUNK + (lane - 32)];
  const float S = finv((unsigned int)(p >> 32));
  float m = S;
#pragma unroll
  for (int off = 32; off > 0; off >>= 1) m = fminf(m, __shfl_xor(m, off, 64));
  unsigned long long mask = __ballot(S < m + MU);

  const float4 x0 = *(const float4*)(xs + (size_t)tok * DIM + lane * 8);
  const float4 x1 = *(const float4*)(xs + (size_t)tok * DIM + lane * 8 + 4);
  const double xd[8] = {x0.x, x0.y, x0.z, x0.w, x1.x, x1.y, x1.z, x1.w};

  double best = __builtin_inf();
  unsigned int besti = 0xFFFFFFFFu;
  while (mask) {
    const int src = __ffsll(mask) - 1;
    mask &= mask - 1;
    const unsigned int ci = (unsigned int)__shfl((int)(unsigned int)p, src, 64);
    const float4 e0 = *(const float4*)(ew + (size_t)ci * DIM + lane * 8);
    const float4 e1 = *(const float4*)(ew + (size_t)ci * DIM + lane * 8 + 4);
    const double ed[8] = {e0.x, e0.y, e0.z, e0.w, e1.x, e1.y, e1.z, e1.w};
    double s = 0.0;
#pragma unroll
    for (int k = 0; k < 8; ++k) {
      const double d = xd[k] - ed[k];
      s = fma(d, d, s);
    }
#pragma unroll
    for (int off = 32; off > 0; off >>= 1) s += __shfl_xor(s, off, 64);
    if (s < best || (s == best && ci < besti)) { best = s; besti = ci; }
  }
  if (lane == 0) g_idx[tok] = besti;
}

// ---------------- gather (bitwise fp32) + loss partials ----------------
__global__ __launch_bounds__(256) void gather_loss_kernel(
    const float* __restrict__ xs, const float* __restrict__ ew,
    const unsigned int* __restrict__ g_idx,
    float* __restrict__ out, float* __restrict__ loss_acc) {
  const int row = blockIdx.x;
  const int t = threadIdx.x;
  const unsigned int idx = g_idx[row];
  const float2 ev = ((const float2*)(ew + (size_t)idx * DIM))[t];
  const float2 xv = ((const float2*)(xs + (size_t)row * DIM))[t];
  ((float2*)(out + (size_t)row * DIM))[t] = ev;
  const float d0 = ev.x - xv.x;
  const float d1 = ev.y - xv.y;
  float s = fmaf(d0, d0, d1 * d1);
#pragma unroll
  for (int off = 32; off > 0; off >>= 1) s += __shfl_down(s, off, 64);
  __shared__ float wsum[4];
  if ((t & 63) == 0) wsum[t >> 6] = s;
  __syncthreads();
  if (t == 0) atomicAdd(loss_acc, wsum[0] + wsum[1] + wsum[2] + wsum[3]);
}

__global__ void loss_finalize(const float* __restrict__ loss_acc,
                              float* __restrict__ out, int out_size) {
  if (threadIdx.x == 0 && blockIdx.x == 0)
    out[out_size - 1] = *loss_acc * 1.25f / (float)((size_t)N_TOK * DIM);
}

// ---------------- fallback: R5 exact fp64 brute (known-passing) ----------------
#define TT 16
#define CT 16
#define KH 256
#define XPAD 516
#define EPAD 260
__global__ __launch_bounds__(256) void brute_argmin_kernel(
    const float* __restrict__ xs, const float* __restrict__ ew,
    unsigned int* __restrict__ g_idx) {
  __shared__ __align__(16) float Xs[TT * XPAD];
  __shared__ __align__(16) float Es[CT * EPAD];
  __shared__ double cand_v[256];
  __shared__ unsigned int cand_i[256];
  const int t = threadIdx.x;
  const int tok0 = blockIdx.x * TT;
#pragma unroll
  for (int i = 0; i < 32; ++i) {
    const int idx = i * 256 + t;
    const int row = idx >> 9, col = idx & 511;
    Xs[row * XPAD + col] = xs[(size_t)(tok0 + row) * DIM + col];
  }
  const int tt = t >> 4;
  const int cl = t & 15;
  double bv = __builtin_inf();
  unsigned int bi = 0u;
  for (int c0 = 0; c0 < K_CODES; c0 += CT) {
    double s0 = 0.0, s1 = 0.0, s2 = 0.0, s3 = 0.0;
#pragma unroll
    for (int h = 0; h < 2; ++h) {
      __syncthreads();
#pragma unroll
      for (int i = 0; i < 16; ++i) {
        const int idx = i * 256 + t;
        const int row = idx >> 8, col = idx & 255;
        Es[row * EPAD + col] = ew[(size_t)(c0 + row) * DIM + h * KH + col];
      }
      __syncthreads();
      const float* __restrict__ xr = &Xs[tt * XPAD + h * KH];
      const float* __restrict__ er = &Es[cl * EPAD];
#pragma unroll 8
      for (int d = 0; d < KH; d += 4) {
        const float4 xf = *(const float4*)(xr + d);
        const float4 ef = *(const float4*)(er + d);
        const double a0 = (double)xf.x - (double)ef.x;
        const double a1 = (double)xf.y - (double)ef.y;
        const double a2 = (double)xf.z - (double)ef.z;
        const double a3 = (double)xf.w - (double)ef.w;
        s0 = fma(a0, a0, s0); s1 = fma(a1, a1, s1);
        s2 = fma(a2, a2, s2); s3 = fma(a3, a3, s3);
      }
    }
    const double s = (s0 + s1) + (s2 + s3);
    if (s < bv) { bv = s; bi = (unsigned int)(c0 + cl); }
  }
  cand_v[t] = bv; cand_i[t] = bi;
  __syncthreads();
  if (t < TT) {
    double mv = __builtin_inf();
    unsigned int mi = 0xFFFFFFFFu;
#pragma unroll
    for (int j = 0; j < 16; ++j) {
      const double v = cand_v[t * 16 + j];
      const unsigned int i = cand_i[t * 16 + j];
      if (v < mv || (v == mv && i < mi)) { mv = v; mi = i; }
    }
    g_idx[tok0 + t] = mi;
  }
}

// ---------------- launch ----------------
extern "C" void kernel_launch(void* const* d_in, const int* in_sizes, int n_in,
                              void* d_out, int out_size, void* d_ws, size_t ws_size,
                              hipStream_t stream) {
  const float* xs = (const float*)d_in[0];
  const float* ew = (const float*)d_in[1];
  if (n_in >= 2 && in_sizes[0] == K_CODES * DIM && in_sizes[1] == N_TOK * DIM) {
    const float* tmp = xs; xs = ew; ew = tmp;
  }
  float* out = (float*)d_out;

  char* w = (char*)d_ws;
  unsigned short* X2 = (unsigned short*)(w);                        // 32 MB
  unsigned short* E2 = (unsigned short*)(w + 33554432);             // 16 MB
  float* enorm = (float*)(w + 50331648);                            // 32 KB
  unsigned long long* buf1 = (unsigned long long*)(w + 50364416);   // 4 MB
  unsigned long long* buf2 = (unsigned long long*)(w + 54558720);   // 4 MB
  unsigned int* g_idx = (unsigned int*)(w + 58753024);              // 64 KB
  float* loss_acc = (float*)(w + 58818560);
  const size_t NEED = 58818624;

  if (ws_size < NEED) {   // fallback: proven R5 exact path
    unsigned int* fg_idx = (unsigned int*)d_ws;
    float* floss = (float*)((char*)d_ws + (size_t)N_TOK * 4);
    hipMemsetAsync(floss, 0, 4, stream);
    brute_argmin_kernel<<<N_TOK / TT, 256, 0, stream>>>(xs, ew, fg_idx);
    gather_loss_kernel<<<N_TOK, 256, 0, stream>>>(xs, ew, fg_idx, out, floss);
    loss_finalize<<<1, 64, 0, stream>>>(floss, out, out_size);
    return;
  }

  hipMemsetAsync(loss_acc, 0, 4, stream);

  split_kernel<<<(N_TOK * 128 + 255) / 256, 256, 0, stream>>>(xs, X2, N_TOK);
  split_kernel<<<(K_CODES * 128 + 255) / 256, 256, 0, stream>>>(ew, E2, K_CODES);
  enorm_kernel<<<K_CODES / 4, 256, 0, stream>>>(ew, enorm);

  dim3 g2(K_CODES / (BN * NT), N_TOK / BM);   // 32 x 128
  gemm_top2_kernel<<<g2, 256, 0, stream>>>(X2, E2, enorm, buf1, buf2);

  rerank_kernel<<<N_TOK / 4, 256, 0, stream>>>(xs, ew, buf1, buf2, g_idx);

  gather_loss_kernel<<<N_TOK, 256, 0, stream>>>(xs, ew, g_idx, out, loss_acc);
  loss_finalize<<<1, 64, 0, stream>>>(loss_acc, out, out_size);
}

// Round 8
// 656.809 us; speedup vs baseline: 14.5463x; 1.4112x over previous
//
#include <hip/hip_runtime.h>
#include <stdint.h>

#define N_TOK   16384
#define DIM     512
#define K_CODES 8192
#define BM      128
#define BN      128
#define BK      32
#define NT      2        // BN-tiles per block (chunk = 256 codes)
#define NCHUNK  32
#define MU      0.25f    // rerank margin; fp16 score err sigma ~0.015

typedef __attribute__((ext_vector_type(8))) _Float16 f16x8;
typedef __attribute__((ext_vector_type(4))) _Float16 f16x4;
typedef __attribute__((ext_vector_type(4))) float f32x4;

__device__ __forceinline__ unsigned int fmono(float f) {
  unsigned int b = __float_as_uint(f);
  unsigned int mask = ((int)b < 0) ? 0xFFFFFFFFu : 0x80000000u;
  return b ^ mask;
}
__device__ __forceinline__ float finv(unsigned int m) {
  return (m & 0x80000000u) ? __uint_as_float(m ^ 0x80000000u)
                           : __uint_as_float(~m);
}
__device__ __forceinline__ void async16(const void* gptr, void* lptr) {
  __builtin_amdgcn_global_load_lds(
      (const __attribute__((address_space(1))) unsigned int*)gptr,
      (__attribute__((address_space(3))) unsigned int*)lptr,
      16, 0, 0);
}

// ---------------- cast X: fp32 -> fp16 ----------------
__global__ __launch_bounds__(256) void castx_kernel(
    const float* __restrict__ in, _Float16* __restrict__ out) {
  const int gid = blockIdx.x * 256 + threadIdx.x;   // one float4 each
  const float4 v = ((const float4*)in)[gid];
  f16x4 h;
  h.x = (_Float16)v.x; h.y = (_Float16)v.y;
  h.z = (_Float16)v.z; h.w = (_Float16)v.w;
  *(f16x4*)(out + (size_t)gid * 4) = h;
}

// ---------------- enorm (fp64-exact) + cast E: fp32 -> fp16 ----------------
__global__ __launch_bounds__(256) void enorm_cast_kernel(
    const float* __restrict__ ew, float* __restrict__ enorm,
    _Float16* __restrict__ E16) {
  const int lane = threadIdx.x & 63;
  const int wid  = threadIdx.x >> 6;
  const int row  = blockIdx.x * 4 + wid;
  const float4 v0 = *(const float4*)(ew + (size_t)row * DIM + lane * 8);
  const float4 v1 = *(const float4*)(ew + (size_t)row * DIM + lane * 8 + 4);
  const float f[8] = {v0.x, v0.y, v0.z, v0.w, v1.x, v1.y, v1.z, v1.w};
  f16x8 h;
  double s = 0.0;
#pragma unroll
  for (int k = 0; k < 8; ++k) {
    s = fma((double)f[k], (double)f[k], s);
    h[k] = (_Float16)f[k];
  }
  *(f16x8*)(E16 + (size_t)row * DIM + lane * 8) = h;
#pragma unroll
  for (int off = 32; off > 0; off >>= 1) s += __shfl_down(s, off, 64);
  if (lane == 0) enorm[row] = (float)s;
}

// ---------------- main: fp16 K=512 GEMM + per-chunk top-2 ----------------
// score(i,k) = ||e_k||^2 - 2*x_i.e_k  (fp16 operands, fp32 MFMA accumulate)
__global__ __launch_bounds__(256) void gemm_top2_kernel(
    const _Float16* __restrict__ X16,   // N x 512
    const _Float16* __restrict__ E16,   // K x 512
    const float* __restrict__ enorm,
    unsigned long long* __restrict__ buf1,   // [token][32] packed top-1
    unsigned long long* __restrict__ buf2) { // [token][32] packed top-2
  __shared__ _Float16 As[BM * BK];
  __shared__ _Float16 Bs[BN * BK];
  __shared__ unsigned long long pack1[BM], pack2[BM], t1[BM], t2[BM];

  const int tid  = threadIdx.x;
  const int lane = tid & 63;
  const int wid  = tid >> 6;
  const int quad = lane >> 4;
  const int l15  = lane & 15;

  const int row0 = blockIdx.y * BM;

  if (tid < BM) { pack1[tid] = ~0ull; pack2[tid] = ~0ull; }

  const int wm = (wid >> 1) * 64;
  const int wn = (wid & 1) * 64;

  // staging (R1==R2==R3-verified): issue covers 16 rows x 64B; lane ->
  // row lane>>2, phys slot lane&3, fetched logical chunk (lane&3)^((lane>>3)&3)
  const int issue0 = wid * 2;
  const int srow   = lane >> 2;
  const int schunk = (lane & 3) ^ ((lane >> 3) & 3);

  for (int nt = 0; nt < NT; ++nt) {
    const int nbase = blockIdx.x * (BN * NT) + nt * BN;

    f32x4 acc[4][4];
#pragma unroll
    for (int i = 0; i < 4; ++i)
#pragma unroll
      for (int j = 0; j < 4; ++j) acc[i][j] = (f32x4){0.f, 0.f, 0.f, 0.f};

    if (tid < BM) { t1[tid] = ~0ull; t2[tid] = ~0ull; }

    for (int k0 = 0; k0 < DIM; k0 += BK) {
#pragma unroll
      for (int q = 0; q < 2; ++q) {
        const int issue = issue0 + q;
        const int r = issue * 16 + srow;
        async16(X16 + (size_t)(row0 + r) * DIM + k0 + schunk * 8,
                (char*)As + issue * 1024);
        async16(E16 + (size_t)(nbase + r) * DIM + k0 + schunk * 8,
                (char*)Bs + issue * 1024);
      }
      __syncthreads();
      f16x8 a[4], b[4];
#pragma unroll
      for (int i = 0; i < 4; ++i) {
        const int ra = wm + i * 16 + l15;
        a[i] = *(const f16x8*)((const char*)As + ra * 64 + ((quad ^ ((ra >> 1) & 3)) * 16));
        const int rb = wn + i * 16 + l15;
        b[i] = *(const f16x8*)((const char*)Bs + rb * 64 + ((quad ^ ((rb >> 1) & 3)) * 16));
      }
#pragma unroll
      for (int i = 0; i < 4; ++i)
#pragma unroll
        for (int j = 0; j < 4; ++j)
          acc[i][j] = __builtin_amdgcn_mfma_f32_16x16x32_f16(a[i], b[j], acc[i][j], 0, 0, 0);
      __syncthreads();
    }

    // epilogue: per-thread top-2 over j; two-phase LDS merge into t1/t2
    float en4[4];
#pragma unroll
    for (int j = 0; j < 4; ++j) en4[j] = enorm[nbase + wn + j * 16 + l15];

    unsigned long long mp1[4], mp2[4];

#pragma unroll
    for (int i = 0; i < 4; ++i) {
      const int mrow = wm + i * 16 + quad * 4;
#pragma unroll
      for (int r = 0; r < 4; ++r) {
        float b1 = __builtin_inff(), b2v = __builtin_inff();
        unsigned int b1i = 0u, b2i = 0u;
#pragma unroll
        for (int j = 0; j < 4; ++j) {
          const float v = fmaf(-2.f, acc[i][j][r], en4[j]);
          const unsigned int ng = (unsigned int)(nbase + wn + j * 16 + l15);
          if (v < b1) { b2v = b1; b2i = b1i; b1 = v; b1i = ng; }
          else if (v < b2v) { b2v = v; b2i = ng; }
        }
        mp1[r] = ((unsigned long long)fmono(b1) << 32) | (unsigned long long)b1i;
        mp2[r] = ((unsigned long long)fmono(b2v) << 32) | (unsigned long long)b2i;
        atomicMin(&t1[mrow + r], mp1[r]);
      }
      __syncthreads();
#pragma unroll
      for (int r = 0; r < 4; ++r) {
        const unsigned int I1 = (unsigned int)t1[mrow + r];
        const unsigned long long cand =
            (((unsigned int)mp1[r]) == I1) ? mp2[r] : mp1[r];
        atomicMin(&t2[mrow + r], cand);
      }
      __syncthreads();
    }

    // streaming merge of (t1,t2) into running (pack1,pack2)
    if (tid < BM) {
      const unsigned long long a = t1[tid], b = t2[tid];
      const unsigned long long g1 = pack1[tid], g2 = pack2[tid];
      if (a < g1) { pack1[tid] = a; pack2[tid] = (g1 < b) ? g1 : b; }
      else        { pack2[tid] = (g2 < a) ? g2 : a; }
    }
    __syncthreads();
  }

  if (tid < BM) {
    buf1[(size_t)(row0 + tid) * NCHUNK + blockIdx.x] = pack1[tid];
    buf2[(size_t)(row0 + tid) * NCHUNK + blockIdx.x] = pack2[tid];
  }
}

// ---------------- fused: exact fp64 rerank + gather + loss ----------------
// One wave per token. Butterfly reductions leave results in ALL lanes, so the
// whole wave agrees on the winner and gathers/writes the output row itself.
__global__ __launch_bounds__(256) void rerank_gather_loss_kernel(
    const float* __restrict__ xs, const float* __restrict__ ew,
    const unsigned long long* __restrict__ buf1,
    const unsigned long long* __restrict__ buf2,
    float* __restrict__ out, float* __restrict__ loss_acc) {
  const int lane = threadIdx.x & 63;
  const int wv = threadIdx.x >> 6;
  const int tok = blockIdx.x * 4 + wv;
  const unsigned long long p = (lane < 32)
      ? buf1[(size_t)tok * NCHUNK + lane]
      : buf2[(size_t)tok * NCHUNK + (lane - 32)];
  const float S = finv((unsigned int)(p >> 32));
  float m = S;
#pragma unroll
  for (int off = 32; off > 0; off >>= 1) m = fminf(m, __shfl_xor(m, off, 64));
  unsigned long long mask = __ballot(S < m + MU);

  const float4 x0 = *(const float4*)(xs + (size_t)tok * DIM + lane * 8);
  const float4 x1 = *(const float4*)(xs + (size_t)tok * DIM + lane * 8 + 4);
  const double xd[8] = {x0.x, x0.y, x0.z, x0.w, x1.x, x1.y, x1.z, x1.w};

  double best = __builtin_inf();
  unsigned int besti = 0xFFFFFFFFu;
  while (mask) {
    const int src = __ffsll(mask) - 1;
    mask &= mask - 1;
    const unsigned int ci = (unsigned int)__shfl((int)(unsigned int)p, src, 64);
    const float4 e0 = *(const float4*)(ew + (size_t)ci * DIM + lane * 8);
    const float4 e1 = *(const float4*)(ew + (size_t)ci * DIM + lane * 8 + 4);
    const double ed[8] = {e0.x, e0.y, e0.z, e0.w, e1.x, e1.y, e1.z, e1.w};
    double s = 0.0;
#pragma unroll
    for (int k = 0; k < 8; ++k) {
      const double d = xd[k] - ed[k];
      s = fma(d, d, s);
    }
#pragma unroll
    for (int off = 32; off > 0; off >>= 1) s += __shfl_xor(s, off, 64);
    if (s < best || (s == best && ci < besti)) { best = s; besti = ci; }
  }

  // gather winner row + loss partial (all lanes agree on besti)
  const float4 e0 = *(const float4*)(ew + (size_t)besti * DIM + lane * 8);
  const float4 e1 = *(const float4*)(ew + (size_t)besti * DIM + lane * 8 + 4);
  *(float4*)(out + (size_t)tok * DIM + lane * 8) = e0;
  *(float4*)(out + (size_t)tok * DIM + lane * 8 + 4) = e1;
  const float ef[8] = {e0.x, e0.y, e0.z, e0.w, e1.x, e1.y, e1.z, e1.w};
  const float xf[8] = {x0.x, x0.y, x0.z, x0.w, x1.x, x1.y, x1.z, x1.w};
  float ls = 0.f;
#pragma unroll
  for (int k = 0; k < 8; ++k) {
    const float d = ef[k] - xf[k];
    ls = fmaf(d, d, ls);
  }
#pragma unroll
  for (int off = 32; off > 0; off >>= 1) ls += __shfl_xor(ls, off, 64);
  if (lane == 0) atomicAdd(loss_acc, ls);
}

__global__ void loss_finalize(const float* __restrict__ loss_acc,
                              float* __restrict__ out, int out_size) {
  if (threadIdx.x == 0 && blockIdx.x == 0)
    out[out_size - 1] = *loss_acc * 1.25f / (float)((size_t)N_TOK * DIM);
}

// ---------------- fallback: R5 exact fp64 brute (known-passing) ----------------
#define TT 16
#define CT 16
#define KH 256
#define XPAD 516
#define EPAD 260
__global__ __launch_bounds__(256) void brute_argmin_kernel(
    const float* __restrict__ xs, const float* __restrict__ ew,
    unsigned int* __restrict__ g_idx) {
  __shared__ __align__(16) float Xs[TT * XPAD];
  __shared__ __align__(16) float Es[CT * EPAD];
  __shared__ double cand_v[256];
  __shared__ unsigned int cand_i[256];
  const int t = threadIdx.x;
  const int tok0 = blockIdx.x * TT;
#pragma unroll
  for (int i = 0; i < 32; ++i) {
    const int idx = i * 256 + t;
    const int row = idx >> 9, col = idx & 511;
    Xs[row * XPAD + col] = xs[(size_t)(tok0 + row) * DIM + col];
  }
  const int tt = t >> 4;
  const int cl = t & 15;
  double bv = __builtin_inf();
  unsigned int bi = 0u;
  for (int c0 = 0; c0 < K_CODES; c0 += CT) {
    double s0 = 0.0, s1 = 0.0, s2 = 0.0, s3 = 0.0;
#pragma unroll
    for (int h = 0; h < 2; ++h) {
      __syncthreads();
#pragma unroll
      for (int i = 0; i < 16; ++i) {
        const int idx = i * 256 + t;
        const int row = idx >> 8, col = idx & 255;
        Es[row * EPAD + col] = ew[(size_t)(c0 + row) * DIM + h * KH + col];
      }
      __syncthreads();
      const float* __restrict__ xr = &Xs[tt * XPAD + h * KH];
      const float* __restrict__ er = &Es[cl * EPAD];
#pragma unroll 8
      for (int d = 0; d < KH; d += 4) {
        const float4 xf = *(const float4*)(xr + d);
        const float4 ef = *(const float4*)(er + d);
        const double a0 = (double)xf.x - (double)ef.x;
        const double a1 = (double)xf.y - (double)ef.y;
        const double a2 = (double)xf.z - (double)ef.z;
        const double a3 = (double)xf.w - (double)ef.w;
        s0 = fma(a0, a0, s0); s1 = fma(a1, a1, s1);
        s2 = fma(a2, a2, s2); s3 = fma(a3, a3, s3);
      }
    }
    const double s = (s0 + s1) + (s2 + s3);
    if (s < bv) { bv = s; bi = (unsigned int)(c0 + cl); }
  }
  cand_v[t] = bv; cand_i[t] = bi;
  __syncthreads();
  if (t < TT) {
    double mv = __builtin_inf();
    unsigned int mi = 0xFFFFFFFFu;
#pragma unroll
    for (int j = 0; j < 16; ++j) {
      const double v = cand_v[t * 16 + j];
      const unsigned int i = cand_i[t * 16 + j];
      if (v < mv || (v == mv && i < mi)) { mv = v; mi = i; }
    }
    g_idx[tok0 + t] = mi;
  }
}

__global__ __launch_bounds__(256) void gather_loss_kernel(
    const float* __restrict__ xs, const float* __restrict__ ew,
    const unsigned int* __restrict__ g_idx,
    float* __restrict__ out, float* __restrict__ loss_acc) {
  const int row = blockIdx.x;
  const int t = threadIdx.x;
  const unsigned int idx = g_idx[row];
  const float2 ev = ((const float2*)(ew + (size_t)idx * DIM))[t];
  const float2 xv = ((const float2*)(xs + (size_t)row * DIM))[t];
  ((float2*)(out + (size_t)row * DIM))[t] = ev;
  const float d0 = ev.x - xv.x;
  const float d1 = ev.y - xv.y;
  float s = fmaf(d0, d0, d1 * d1);
#pragma unroll
  for (int off = 32; off > 0; off >>= 1) s += __shfl_down(s, off, 64);
  __shared__ float wsum[4];
  if ((t & 63) == 0) wsum[t >> 6] = s;
  __syncthreads();
  if (t == 0) atomicAdd(loss_acc, wsum[0] + wsum[1] + wsum[2] + wsum[3]);
}

// ---------------- launch ----------------
extern "C" void kernel_launch(void* const* d_in, const int* in_sizes, int n_in,
                              void* d_out, int out_size, void* d_ws, size_t ws_size,
                              hipStream_t stream) {
  const float* xs = (const float*)d_in[0];
  const float* ew = (const float*)d_in[1];
  if (n_in >= 2 && in_sizes[0] == K_CODES * DIM && in_sizes[1] == N_TOK * DIM) {
    const float* tmp = xs; xs = ew; ew = tmp;
  }
  float* out = (float*)d_out;

  char* w = (char*)d_ws;
  _Float16* X16 = (_Float16*)(w);                                   // 16 MB
  _Float16* E16 = (_Float16*)(w + 16777216);                        // 8 MB
  float* enorm = (float*)(w + 25165824);                            // 32 KB
  unsigned long long* buf1 = (unsigned long long*)(w + 25198592);   // 4 MB
  unsigned long long* buf2 = (unsigned long long*)(w + 29392896);   // 4 MB
  float* loss_acc = (float*)(w + 33587200);
  const size_t NEED = 33587264;

  if (ws_size < NEED) {   // fallback: proven R5 exact path
    unsigned int* fg_idx = (unsigned int*)d_ws;
    float* floss = (float*)((char*)d_ws + (size_t)N_TOK * 4);
    hipMemsetAsync(floss, 0, 4, stream);
    brute_argmin_kernel<<<N_TOK / TT, 256, 0, stream>>>(xs, ew, fg_idx);
    gather_loss_kernel<<<N_TOK, 256, 0, stream>>>(xs, ew, fg_idx, out, floss);
    loss_finalize<<<1, 64, 0, stream>>>(floss, out, out_size);
    return;
  }

  hipMemsetAsync(loss_acc, 0, 4, stream);

  castx_kernel<<<N_TOK * DIM / 4 / 256, 256, 0, stream>>>(xs, X16);
  enorm_cast_kernel<<<K_CODES / 4, 256, 0, stream>>>(ew, enorm, E16);

  dim3 g2(K_CODES / (BN * NT), N_TOK / BM);   // 32 x 128
  gemm_top2_kernel<<<g2, 256, 0, stream>>>(X16, E16, enorm, buf1, buf2);

  rerank_gather_loss_kernel<<<N_TOK / 4, 256, 0, stream>>>(xs, ew, buf1, buf2,
                                                           out, loss_acc);
  loss_finalize<<<1, 64, 0, stream>>>(loss_acc, out, out_size);
}